// Round 11
// baseline (1920.974 us; speedup 1.0000x reference)
//
#include <hip/hip_runtime.h>

typedef __bf16 bf16x8 __attribute__((ext_vector_type(8)));
typedef float f32x16 __attribute__((ext_vector_type(16)));

#define LN_EPS 1e-5f
#define AS1 __attribute__((address_space(1)))
#define AS3 __attribute__((address_space(3)))

__device__ __forceinline__ unsigned f2bf_rne(float f) {
    unsigned x = __float_as_uint(f);
    return (x + 0x7fffu + ((x >> 16) & 1u)) >> 16;  // round-to-nearest-even, finite inputs
}

__device__ __forceinline__ float bf2f(unsigned short u) {
    return __uint_as_float((unsigned)u << 16);
}

// ---------------------------------------------------------------------------
// Pack conv_w fp32 (4,27,128,128) -> bf16, K-packed by 8: Wp[oc][k>>3][n][k&7]
// so MFMA B-fragments are contiguous 16B.
// ---------------------------------------------------------------------------
__global__ void pack_w_kernel(const float* __restrict__ cw, unsigned short* __restrict__ Wp, int E) {
    int idx = blockIdx.x * 256 + threadIdx.x;
    if (idx >= E) return;
    float v = cw[idx];
    int n  = idx & 127;
    int c  = (idx >> 7) & 127;
    int oc = idx >> 14;
    Wp[oc * 16384 + (c >> 3) * 1024 + n * 8 + (c & 7)] = (unsigned short)f2bf_rne(v);
}

// Pack w1 fp32 (128,64) -> bf16 K-packed: Wp1[k>>3][n][k&7], 8192 elems.
__global__ void pack_w1_kernel(const float* __restrict__ w1, unsigned short* __restrict__ Wp1) {
    int idx = blockIdx.x * 256 + threadIdx.x;
    if (idx >= 8192) return;
    int k = idx >> 6, n = idx & 63;
    Wp1[(k >> 3) * 512 + n * 8 + (k & 7)] = (unsigned short)f2bf_rne(w1[k * 64 + n]);
}

// ---------------------------------------------------------------------------
// Prep: gather table T[o][m] = found ? nbr_idx : M (dummy zero row),
// and per-64-row-group activity bitmask act64[m>>6] (one group per wave).
// ---------------------------------------------------------------------------
__global__ void prep_nbr_kernel(const int* __restrict__ nbr_idx, const float* __restrict__ nbr_mask,
                                int* __restrict__ T, unsigned* __restrict__ act64, int M) {
    int m = blockIdx.x * 256 + threadIdx.x;
    if (m >= M) return;
    unsigned bits = 0;
#pragma unroll
    for (int o = 0; o < 27; ++o) {
        bool f = nbr_mask[m * 27 + o] != 0.f;
        int g = f ? nbr_idx[m * 27 + o] : M;
        T[o * M + m] = g;
        bits |= (f ? 1u : 0u) << o;
    }
    atomicOr(&act64[m >> 6], bits);
}

// ---------------------------------------------------------------------------
// Encoder: f = relu(LN(gp @ w_enc + b_enc)), scatter-add into voxel sums.
// ---------------------------------------------------------------------------
__global__ __launch_bounds__(256) void encode_kernel(
    const float* __restrict__ gp, const float* __restrict__ w_enc,
    const float* __restrict__ b_enc, const float* __restrict__ ln_g,
    const float* __restrict__ ln_b, const int* __restrict__ inv_idx,
    float* __restrict__ vsum, float* __restrict__ cnt, int N)
{
    int p = blockIdx.x * 4 + (threadIdx.x >> 6);
    int lane = threadIdx.x & 63;
    if (p >= N) return;
    float gv[14];
#pragma unroll
    for (int i = 0; i < 14; ++i) gv[i] = gp[p * 14 + i];
    float f0 = b_enc[lane], f1 = b_enc[lane + 64];
#pragma unroll
    for (int i = 0; i < 14; ++i) {
        f0 = fmaf(gv[i], w_enc[i * 128 + lane], f0);
        f1 = fmaf(gv[i], w_enc[i * 128 + lane + 64], f1);
    }
    float s = f0 + f1;
#pragma unroll
    for (int off = 32; off; off >>= 1) s += __shfl_xor(s, off);
    float mean = s * 0.0078125f;
    float d0 = f0 - mean, d1 = f1 - mean;
    float v = d0 * d0 + d1 * d1;
#pragma unroll
    for (int off = 32; off; off >>= 1) v += __shfl_xor(v, off);
    float rs = rsqrtf(v * 0.0078125f + LN_EPS);
    float h0 = d0 * rs * ln_g[lane] + ln_b[lane];
    float h1 = d1 * rs * ln_g[lane + 64] + ln_b[lane + 64];
    h0 = h0 > 0.f ? h0 : 0.f;
    h1 = h1 > 0.f ? h1 : 0.f;
    int vx = inv_idx[p];
    atomicAdd(&vsum[vx * 128 + lane], h0);
    atomicAdd(&vsum[vx * 128 + lane + 64], h1);
    if (lane == 0) atomicAdd(&cnt[vx], 1.0f);
}

// ---------------------------------------------------------------------------
// Voxel mean: A_bf16 = vsum / cnt
// ---------------------------------------------------------------------------
__global__ void vox_mean_kernel(const float* __restrict__ vsum, const float* __restrict__ cnt,
                                unsigned short* __restrict__ out, int total4) {
    int idx = blockIdx.x * 256 + threadIdx.x;
    if (idx >= total4) return;
    int e0 = idx * 4;
    float r = 1.f / cnt[e0 >> 7];
    float4 v = *(const float4*)(vsum + e0);
    uint2 pk;
    pk.x = f2bf_rne(v.x * r) | (f2bf_rne(v.y * r) << 16);
    pk.y = f2bf_rne(v.z * r) | (f2bf_rne(v.w * r) << 16);
    *(uint2*)(out + e0) = pk;
}

// ---------------------------------------------------------------------------
// Submanifold conv: y[m] = sum_o x[T[o][m]] @ W[o]   (T==M -> zero row)
// COALESCED-GATHER version. Diagnosis (R0-R10): per-CU TA/vector-memory
// service of address-divergent gathers (64 distinct lines per instruction)
// was the invariant ~21% MfmaUtil binder. Fix: 16 lanes cooperatively load
// one row (4 rows x 4 contiguous lines per global_load_lds, per-lane global
// src + wave-uniform linear LDS dest), staging each offset's 64 rows into a
// PER-WAVE private 16KB LDS buffer (double-buffered; 128KB/block). Wave
// syncs only its own DMAs: one vmcnt(0) per offset, issued a full MFMA
// phase after the DMAs -> ~free. A-fragments read back via ds_read_b128
// with XOR chunk swizzle (c ^= row&7 on BOTH global-src and read side;
// 4-way conflict only). Row indices reach loading lanes via __shfl of each
// lane's own T value. B: in-offset 4-slot register pipe from L2. No
// __syncthreads. XCD-bijective tile swizzle.
// ---------------------------------------------------------------------------
__global__ __launch_bounds__(256, 1) void subm_conv_kernel(
    const unsigned short* __restrict__ xin,   // (M+1) x 128 bf16, row M zeros
    const unsigned short* __restrict__ Wp,    // 27 x 16 x 128 x 8 bf16 packed
    const int* __restrict__ T, const unsigned* __restrict__ act64,
    float* __restrict__ yout, float* __restrict__ stats, int M)
{
    __shared__ uint4 Abuf[8192];  // 4 waves x 2 bufs x 64 rows x 256B = 128KB

    const int tid = threadIdx.x;
    const int lane = tid & 63;
    const int w = tid >> 6;

    // ---- T1: bijective XCD swizzle (m204): contiguous tile chunk per XCD ----
    const int nwg = gridDim.x;
    const int orig = blockIdx.x;
    const int xcd = orig & 7;
    const int q8 = nwg >> 3, r8 = nwg & 7;
    const int tile = (xcd < r8 ? xcd * (q8 + 1) : r8 * (q8 + 1) + (xcd - r8) * q8) + (orig >> 3);

    const int m0 = tile * 256;
    const int rw = w * 64;           // 64 rows per wave (2 row-blocks of 32)
    const int q = lane >> 5;
    const int l31 = lane & 31;
    const int wbase = w * 2048;      // wave's LDS base, in uint4 units

    int rowt = m0 + rw + lane;       // the row this lane OWNS (T reads)
    if (rowt >= M) rowt = M - 1;

    f32x16 acc0[4], acc1[4];
#pragma unroll
    for (int t = 0; t < 4; ++t)
#pragma unroll
        for (int r = 0; r < 16; ++r) { acc0[t][r] = 0.f; acc1[t][r] = 0.f; }

    const uint4* xin4 = (const uint4*)xin;
    const bf16x8* WpB = (const bf16x8*)Wp;

    unsigned amask = act64[tile * 4 + w];  // per-wave mask

    // DMA macro: stage offset (using per-lane T value TV) into buffer BUFSEL.
    // Instruction j loads rows 4j..4j+3: lane l -> row 4j+(l>>4), global chunk
    // (l&15)^(rloc&7) (inverse swizzle), LDS linear (lane*16 off wave base).
#define STAGE_A(TV, BUFSEL)                                                           \
    _Pragma("unroll")                                                                 \
    for (int j = 0; j < 16; ++j) {                                                    \
        int rloc = 4 * j + (lane >> 4);                                               \
        int g = __shfl((TV), rloc);                                                   \
        int csrc = (lane & 15) ^ (rloc & 7);                                          \
        __builtin_amdgcn_global_load_lds(                                             \
            (const AS1 unsigned int*)(xin4 + (size_t)g * 16 + csrc),                  \
            (AS3 unsigned int*)(Abuf + wbase + (BUFSEL) * 1024 + j * 64), 16, 0, 0);  \
    }

    if (amask) {
        // ---- prologue: stage first offset (latency exposed once) ----
        int o = __ffs(amask) - 1; amask &= amask - 1;
        int tcur = T[o * M + rowt];
        STAGE_A(tcur, 0);
        int o1 = -1, t1 = 0;
        if (amask) {
            o1 = __ffs(amask) - 1; amask &= amask - 1;
            t1 = T[o1 * M + rowt];
        }
        int buf = 0;

        while (true) {
            // wait for this offset's DMAs (issued >= one full phase ago,
            // except the prologue's). B loads from the previous phase were
            // all consumed -> this is ~free in steady state.
            asm volatile("s_waitcnt vmcnt(0)" ::: "memory");

            // ---- prefetch T for the offset after next ----
            int o2 = -1, t2 = 0;
            if (amask) {
                o2 = __ffs(amask) - 1; amask &= amask - 1;
                t2 = T[o2 * M + rowt];
            }
            const bool more = (o1 >= 0);

            // ---- issue next offset's DMAs into the other buffer ----
            if (more) STAGE_A(t1, buf ^ 1);

            // ---- B pipe preload (slots 0..2) for current offset ----
            const bf16x8* Bo = WpB + (size_t)o * 2048;
            bf16x8 bp[4][4];
#pragma unroll
            for (int s = 0; s < 3; ++s) {
                int kb = (s << 1) | q;
                bp[s][0] = Bo[kb * 128 + l31];
                bp[s][1] = Bo[kb * 128 + 32 + l31];
                bp[s][2] = Bo[kb * 128 + 64 + l31];
                bp[s][3] = Bo[kb * 128 + 96 + l31];
            }

            // ---- A fragments from this wave's staged buffer (swizzled) ----
            const bf16x8* Ab = (const bf16x8*)(Abuf + wbase + buf * 1024);
            bf16x8 af0[8], af1[8];
#pragma unroll
            for (int ks = 0; ks < 8; ++ks) {
                int c = (2 * ks + q) ^ (l31 & 7);
                af0[ks] = Ab[l31 * 16 + c];
                af1[ks] = Ab[(32 + l31) * 16 + c];
            }

            __builtin_amdgcn_s_setprio(1);
#pragma unroll
            for (int ks = 0; ks < 8; ++ks) {
                const int cs = ks & 3;
                const int ls = (ks + 3) & 3;
                bf16x8 bc0 = bp[cs][0], bc1 = bp[cs][1], bc2 = bp[cs][2], bc3 = bp[cs][3];
                if (ks < 5) {
                    int kb = ((ks + 3) << 1) | q;
                    bp[ls][0] = Bo[kb * 128 + l31];
                    bp[ls][1] = Bo[kb * 128 + 32 + l31];
                    bp[ls][2] = Bo[kb * 128 + 64 + l31];
                    bp[ls][3] = Bo[kb * 128 + 96 + l31];
                }
                acc0[0] = __builtin_amdgcn_mfma_f32_32x32x16_bf16(af0[ks], bc0, acc0[0], 0, 0, 0);
                acc1[0] = __builtin_amdgcn_mfma_f32_32x32x16_bf16(af1[ks], bc0, acc1[0], 0, 0, 0);
                acc0[1] = __builtin_amdgcn_mfma_f32_32x32x16_bf16(af0[ks], bc1, acc0[1], 0, 0, 0);
                acc1[1] = __builtin_amdgcn_mfma_f32_32x32x16_bf16(af1[ks], bc1, acc1[1], 0, 0, 0);
                acc0[2] = __builtin_amdgcn_mfma_f32_32x32x16_bf16(af0[ks], bc2, acc0[2], 0, 0, 0);
                acc1[2] = __builtin_amdgcn_mfma_f32_32x32x16_bf16(af1[ks], bc2, acc1[2], 0, 0, 0);
                acc0[3] = __builtin_amdgcn_mfma_f32_32x32x16_bf16(af0[ks], bc3, acc0[3], 0, 0, 0);
                acc1[3] = __builtin_amdgcn_mfma_f32_32x32x16_bf16(af1[ks], bc3, acc1[3], 0, 0, 0);
            }
            __builtin_amdgcn_s_setprio(0);

            if (!more) break;
            o = o1; o1 = o2; t1 = t2; buf ^= 1;
        }
    }
#undef STAGE_A

    // ---- epilogue: store y + BN stats (tail rows contribute 0 to stats) ----
#pragma unroll
    for (int tn = 0; tn < 4; ++tn) {
        int col = tn * 32 + l31;
        float s = 0.f, sq = 0.f;
#pragma unroll
        for (int r = 0; r < 16; ++r) {
            int rloc = (r & 3) + 8 * (r >> 2) + 4 * q + rw;
            int grow = m0 + rloc;
            float v = (grow < M) ? acc0[tn][r] : 0.f;
            if (grow < M) yout[grow * 128 + col] = v;
            s += v; sq += v * v;
        }
#pragma unroll
        for (int r = 0; r < 16; ++r) {
            int rloc = (r & 3) + 8 * (r >> 2) + 4 * q + rw + 32;
            int grow = m0 + rloc;
            float v = (grow < M) ? acc1[tn][r] : 0.f;
            if (grow < M) yout[grow * 128 + col] = v;
            s += v; sq += v * v;
        }
        s += __shfl_xor(s, 32);
        sq += __shfl_xor(sq, 32);
        if (lane < 32) {
            atomicAdd(&stats[col], s);
            atomicAdd(&stats[128 + col], sq);
        }
    }
}

// ---------------------------------------------------------------------------
// BN (batch stats) + ReLU -> bf16 (optionally + residual)
// ---------------------------------------------------------------------------
__global__ void bn_relu_kernel(const float* __restrict__ y, const float* __restrict__ stats,
                               const float* __restrict__ g, const float* __restrict__ b,
                               unsigned short* __restrict__ out, int total4, float invM) {
    int idx = blockIdx.x * 256 + threadIdx.x;
    if (idx >= total4) return;
    int e0 = idx * 4;
    int c0 = e0 & 127;
    float4 yv = *(const float4*)(y + e0);
    float h[4];
    const float* yp = (const float*)&yv;
#pragma unroll
    for (int j = 0; j < 4; ++j) {
        int c = c0 + j;
        float mean = stats[c] * invM;
        float var = stats[128 + c] * invM - mean * mean;
        float sc = g[c] * rsqrtf(var + LN_EPS);
        float sh = b[c] - mean * sc;
        float vv = yp[j] * sc + sh;
        h[j] = vv > 0.f ? vv : 0.f;
    }
    uint2 pk;
    pk.x = f2bf_rne(h[0]) | (f2bf_rne(h[1]) << 16);
    pk.y = f2bf_rne(h[2]) | (f2bf_rne(h[3]) << 16);
    *(uint2*)(out + e0) = pk;
}

__global__ void bn_relu_res_kernel(const float* __restrict__ y, const float* __restrict__ stats,
                                   const float* __restrict__ g, const float* __restrict__ b,
                                   const unsigned short* __restrict__ idn,
                                   unsigned short* __restrict__ out, int total4, float invM) {
    int idx = blockIdx.x * 256 + threadIdx.x;
    if (idx >= total4) return;
    int e0 = idx * 4;
    int c0 = e0 & 127;
    float4 yv = *(const float4*)(y + e0);
    uint2 iv = *(const uint2*)(idn + e0);
    float id[4];
    id[0] = __uint_as_float(iv.x << 16);
    id[1] = __uint_as_float(iv.x & 0xffff0000u);
    id[2] = __uint_as_float(iv.y << 16);
    id[3] = __uint_as_float(iv.y & 0xffff0000u);
    float h[4];
    const float* yp = (const float*)&yv;
#pragma unroll
    for (int j = 0; j < 4; ++j) {
        int c = c0 + j;
        float mean = stats[c] * invM;
        float var = stats[128 + c] * invM - mean * mean;
        float sc = g[c] * rsqrtf(var + LN_EPS);
        float sh = b[c] - mean * sc;
        float vv = yp[j] * sc + sh + id[j];
        h[j] = vv > 0.f ? vv : 0.f;
    }
    uint2 pk;
    pk.x = f2bf_rne(h[0]) | (f2bf_rne(h[1]) << 16);
    pk.y = f2bf_rne(h[2]) | (f2bf_rne(h[3]) << 16);
    *(uint2*)(out + e0) = pk;
}

// ---------------------------------------------------------------------------
// Head over voxels: Dv = relu(A @ w1 + b1) @ w2   (per-voxel, M x 14)
// ---------------------------------------------------------------------------
__global__ __launch_bounds__(256) void head_vox_kernel(
    const unsigned short* __restrict__ A,    // (M+1) x 128 bf16
    const unsigned short* __restrict__ Wp1,  // 8 x 64 x 8 bf16 packed
    const float* __restrict__ b1, const float* __restrict__ w2,
    const float* __restrict__ b2, float* __restrict__ Dv, int M)
{
    __shared__ uint4 W1s[1024];              // 16 KB (uint4: 16B-aligned reads)
    __shared__ unsigned short Hs[8192];      // 128 x 64 bf16, chunk-swizzled, 16 KB
    __shared__ float w2s[896];               // 64 x 14

    const int tid = threadIdx.x;
    const int lane = tid & 63;
    const int w = tid >> 6;
    const int m0 = blockIdx.x * 128;
    const int rw = w * 32;
    const int q = lane >> 5;
    const int l31 = lane & 31;
    int myrow = m0 + rw + l31;
    if (myrow > M) myrow = M;  // row M is zeros

    for (int i = tid; i < 1024; i += 256) W1s[i] = ((const uint4*)Wp1)[i];
    for (int i = tid; i < 896; i += 256) w2s[i] = w2[i];

    const uint4* xin4 = (const uint4*)A;
    uint4 af[8];
#pragma unroll
    for (int j = 0; j < 8; ++j) af[j] = xin4[myrow * 16 + 2 * j + q];

    f32x16 acc[2];
#pragma unroll
    for (int t = 0; t < 2; ++t)
#pragma unroll
        for (int r = 0; r < 16; ++r) acc[t][r] = 0.f;

    __syncthreads();

#pragma unroll
    for (int ks = 0; ks < 8; ++ks) {
        int kb = (ks << 1) | q;
        bf16x8 a = *(const bf16x8*)&af[ks];
#pragma unroll
        for (int tn = 0; tn < 2; ++tn) {
            bf16x8 b = ((const bf16x8*)W1s)[kb * 64 + tn * 32 + l31];
            acc[tn] = __builtin_amdgcn_mfma_f32_32x32x16_bf16(a, b, acc[tn], 0, 0, 0);
        }
    }

#pragma unroll
    for (int tn = 0; tn < 2; ++tn) {
        int col = tn * 32 + l31;
        float bias = b1[col];
        int ch = col >> 3, ce = col & 7;
#pragma unroll
        for (int r = 0; r < 16; ++r) {
            int rloc = (r & 3) + 8 * (r >> 2) + 4 * q + rw;
            float v = acc[tn][r] + bias;
            v = v > 0.f ? v : 0.f;
            Hs[rloc * 64 + (ch ^ (rloc & 7)) * 8 + ce] = (unsigned short)f2bf_rne(v);
        }
    }
    __syncthreads();

    int r2 = tid >> 1;
    int c0 = (tid & 1) * 7;
    float o[7];
#pragma unroll
    for (int j = 0; j < 7; ++j) o[j] = b2[c0 + j];
#pragma unroll
    for (int c = 0; c < 8; ++c) {
        bf16x8 hv = ((const bf16x8*)Hs)[r2 * 8 + (c ^ (r2 & 7))];
#pragma unroll
        for (int e = 0; e < 8; ++e) {
            float h = bf2f(((const unsigned short*)&hv)[e]);
            int k = c * 8 + e;
#pragma unroll
            for (int j = 0; j < 7; ++j) o[j] = fmaf(h, w2s[k * 14 + c0 + j], o[j]);
        }
    }
    int grow = m0 + r2;
    if (grow < M) {
#pragma unroll
        for (int j = 0; j < 7; ++j) Dv[grow * 14 + c0 + j] = o[j];
    }
}

// out[p] = gp[p,:14] + Dv[inv_idx[p]]
__global__ void head_scatter_kernel(const float* __restrict__ gp, const float* __restrict__ Dv,
                                    const int* __restrict__ inv_idx, float* __restrict__ out, int N) {
    int p = blockIdx.x * 256 + threadIdx.x;
    if (p >= N) return;
    int vx = inv_idx[p];
#pragma unroll
    for (int c = 0; c < 14; ++c) out[p * 14 + c] = gp[p * 14 + c] + Dv[vx * 14 + c];
}

// ---------------------------------------------------------------------------
extern "C" void kernel_launch(void* const* d_in, const int* in_sizes, int n_in,
                              void* d_out, int out_size, void* d_ws, size_t ws_size,
                              hipStream_t stream) {
    const float* gp       = (const float*)d_in[0];
    const float* w_enc    = (const float*)d_in[1];
    const float* b_enc    = (const float*)d_in[2];
    const float* ln_g     = (const float*)d_in[3];
    const float* ln_b     = (const float*)d_in[4];
    const float* conv_w   = (const float*)d_in[5];
    const float* bn_g     = (const float*)d_in[6];
    const float* bn_b     = (const float*)d_in[7];
    const float* w1       = (const float*)d_in[8];
    const float* b1       = (const float*)d_in[9];
    const float* w2       = (const float*)d_in[10];
    const float* b2       = (const float*)d_in[11];
    const float* nbr_mask = (const float*)d_in[12];
    const int*   inv_idx  = (const int*)d_in[13];
    const int*   nbr_idx  = (const int*)d_in[14];

    const int N = in_sizes[0] / 14;
    const int M = in_sizes[12] / 27;
    const int ntiles = (M + 127) / 128;      // 128-row tiling (head_vox)
    const int ntiles256 = (M + 255) / 256;   // 256-row tiling (subm_conv)

    char* ws = (char*)d_ws;
    size_t off = 0;
    unsigned short* Wp = (unsigned short*)(ws + off); off += (size_t)4 * 27 * 16384 * 2;
    unsigned short* A  = (unsigned short*)(ws + off); off += (size_t)(M + 1) * 128 * 2;
    unsigned short* H  = (unsigned short*)(ws + off); off += (size_t)(M + 1) * 128 * 2;
    float* Yraw  = (float*)(ws + off);
    size_t zoff = off;
    off += (size_t)M * 128 * 4;
    float* cnt   = (float*)(ws + off); off += (size_t)M * 4;
    float* stats = (float*)(ws + off); off += 4 * 256 * 4;
    unsigned* act64 = (unsigned*)(ws + off); off += (size_t)ntiles256 * 4 * 4;
    size_t zbytes = off - zoff;
    int* T = (int*)(ws + off); off += (size_t)27 * M * 4;
    unsigned short* Wp1 = (unsigned short*)(ws + off); off += 8192 * 2;
    float* Dv = Yraw;

    hipMemsetAsync(Yraw, 0, zbytes, stream);
    hipMemsetAsync(A + (size_t)M * 128, 0, 256, stream);
    hipMemsetAsync(H + (size_t)M * 128, 0, 256, stream);

    const int E = 4 * 27 * 128 * 128;
    pack_w_kernel<<<(E + 255) / 256, 256, 0, stream>>>(conv_w, Wp, E);
    pack_w1_kernel<<<32, 256, 0, stream>>>(w1, Wp1);
    prep_nbr_kernel<<<(M + 255) / 256, 256, 0, stream>>>(nbr_idx, nbr_mask, T, act64, M);
    encode_kernel<<<(N + 3) / 4, 256, 0, stream>>>(gp, w_enc, b_enc, ln_g, ln_b, inv_idx, Yraw, cnt, N);
    const int total4 = M * 32;
    vox_mean_kernel<<<(total4 + 255) / 256, 256, 0, stream>>>(Yraw, cnt, A, total4);

    const float invM = 1.f / (float)M;
    for (int blk = 0; blk < 2; ++blk) {
        int c0 = 2 * blk, c1 = 2 * blk + 1;
        subm_conv_kernel<<<ntiles256, 256, 0, stream>>>(
            A, Wp + (size_t)c0 * 27 * 16384, T, act64, Yraw, stats + c0 * 256, M);
        bn_relu_kernel<<<(total4 + 255) / 256, 256, 0, stream>>>(
            Yraw, stats + c0 * 256, bn_g + c0 * 128, bn_b + c0 * 128, H, total4, invM);
        subm_conv_kernel<<<ntiles256, 256, 0, stream>>>(
            H, Wp + (size_t)c1 * 27 * 16384, T, act64, Yraw, stats + c1 * 256, M);
        bn_relu_res_kernel<<<(total4 + 255) / 256, 256, 0, stream>>>(
            Yraw, stats + c1 * 256, bn_g + c1 * 128, bn_b + c1 * 128, A, A, total4, invM);
    }
    head_vox_kernel<<<ntiles, 256, 0, stream>>>(A, Wp1, b1, w2, b2, Dv, M);
    head_scatter_kernel<<<(N + 255) / 256, 256, 0, stream>>>(gp, Dv, inv_idx, (float*)d_out, N);
}

// Round 12
// 1378.818 us; speedup vs baseline: 1.3932x; 1.3932x over previous
//
#include <hip/hip_runtime.h>

typedef __bf16 bf16x8 __attribute__((ext_vector_type(8)));
typedef float f32x16 __attribute__((ext_vector_type(16)));

#define LN_EPS 1e-5f

__device__ __forceinline__ unsigned f2bf_rne(float f) {
    unsigned x = __float_as_uint(f);
    return (x + 0x7fffu + ((x >> 16) & 1u)) >> 16;  // round-to-nearest-even, finite inputs
}

__device__ __forceinline__ float bf2f(unsigned short u) {
    return __uint_as_float((unsigned)u << 16);
}

// ---------------------------------------------------------------------------
// Pack conv_w fp32 (4,27,128,128) -> bf16, K-packed by 8: Wp[oc][k>>3][n][k&7]
// so MFMA B-fragments are contiguous 16B.
// ---------------------------------------------------------------------------
__global__ void pack_w_kernel(const float* __restrict__ cw, unsigned short* __restrict__ Wp, int E) {
    int idx = blockIdx.x * 256 + threadIdx.x;
    if (idx >= E) return;
    float v = cw[idx];
    int n  = idx & 127;
    int c  = (idx >> 7) & 127;
    int oc = idx >> 14;
    Wp[oc * 16384 + (c >> 3) * 1024 + n * 8 + (c & 7)] = (unsigned short)f2bf_rne(v);
}

// Pack w1 fp32 (128,64) -> bf16 K-packed: Wp1[k>>3][n][k&7], 8192 elems.
__global__ void pack_w1_kernel(const float* __restrict__ w1, unsigned short* __restrict__ Wp1) {
    int idx = blockIdx.x * 256 + threadIdx.x;
    if (idx >= 8192) return;
    int k = idx >> 6, n = idx & 63;
    Wp1[(k >> 3) * 512 + n * 8 + (k & 7)] = (unsigned short)f2bf_rne(w1[k * 64 + n]);
}

// ---------------------------------------------------------------------------
// Prep: gather table T[o][m] = found ? nbr_idx : M (dummy zero row),
// and per-64-row-group activity bitmask act64[m>>6] (one group per wave).
// ---------------------------------------------------------------------------
__global__ void prep_nbr_kernel(const int* __restrict__ nbr_idx, const float* __restrict__ nbr_mask,
                                int* __restrict__ T, unsigned* __restrict__ act64, int M) {
    int m = blockIdx.x * 256 + threadIdx.x;
    if (m >= M) return;
    unsigned bits = 0;
#pragma unroll
    for (int o = 0; o < 27; ++o) {
        bool f = nbr_mask[m * 27 + o] != 0.f;
        int g = f ? nbr_idx[m * 27 + o] : M;
        T[o * M + m] = g;
        bits |= (f ? 1u : 0u) << o;
    }
    atomicOr(&act64[m >> 6], bits);
}

// ---------------------------------------------------------------------------
// Encoder: f = relu(LN(gp @ w_enc + b_enc)), scatter-add into voxel sums.
// ---------------------------------------------------------------------------
__global__ __launch_bounds__(256) void encode_kernel(
    const float* __restrict__ gp, const float* __restrict__ w_enc,
    const float* __restrict__ b_enc, const float* __restrict__ ln_g,
    const float* __restrict__ ln_b, const int* __restrict__ inv_idx,
    float* __restrict__ vsum, float* __restrict__ cnt, int N)
{
    int p = blockIdx.x * 4 + (threadIdx.x >> 6);
    int lane = threadIdx.x & 63;
    if (p >= N) return;
    float gv[14];
#pragma unroll
    for (int i = 0; i < 14; ++i) gv[i] = gp[p * 14 + i];
    float f0 = b_enc[lane], f1 = b_enc[lane + 64];
#pragma unroll
    for (int i = 0; i < 14; ++i) {
        f0 = fmaf(gv[i], w_enc[i * 128 + lane], f0);
        f1 = fmaf(gv[i], w_enc[i * 128 + lane + 64], f1);
    }
    float s = f0 + f1;
#pragma unroll
    for (int off = 32; off; off >>= 1) s += __shfl_xor(s, off);
    float mean = s * 0.0078125f;
    float d0 = f0 - mean, d1 = f1 - mean;
    float v = d0 * d0 + d1 * d1;
#pragma unroll
    for (int off = 32; off; off >>= 1) v += __shfl_xor(v, off);
    float rs = rsqrtf(v * 0.0078125f + LN_EPS);
    float h0 = d0 * rs * ln_g[lane] + ln_b[lane];
    float h1 = d1 * rs * ln_g[lane + 64] + ln_b[lane + 64];
    h0 = h0 > 0.f ? h0 : 0.f;
    h1 = h1 > 0.f ? h1 : 0.f;
    int vx = inv_idx[p];
    atomicAdd(&vsum[vx * 128 + lane], h0);
    atomicAdd(&vsum[vx * 128 + lane + 64], h1);
    if (lane == 0) atomicAdd(&cnt[vx], 1.0f);
}

// ---------------------------------------------------------------------------
// Voxel mean: A_bf16 = vsum / cnt
// ---------------------------------------------------------------------------
__global__ void vox_mean_kernel(const float* __restrict__ vsum, const float* __restrict__ cnt,
                                unsigned short* __restrict__ out, int total4) {
    int idx = blockIdx.x * 256 + threadIdx.x;
    if (idx >= total4) return;
    int e0 = idx * 4;
    float r = 1.f / cnt[e0 >> 7];
    float4 v = *(const float4*)(vsum + e0);
    uint2 pk;
    pk.x = f2bf_rne(v.x * r) | (f2bf_rne(v.y * r) << 16);
    pk.y = f2bf_rne(v.z * r) | (f2bf_rne(v.w * r) << 16);
    *(uint2*)(out + e0) = pk;
}

// ---------------------------------------------------------------------------
// Submanifold conv: y[m] = sum_o x[T[o][m]] @ W[o]   (T==M -> zero row)
// R10 structure (best verified: 245us, MfmaUtil 23.2, clean counters):
// 64 rows/wave, 4 waves/block, barrier-free, LDS-free, B-fragment 4-slot
// rotating register pipe with CROSS-OFFSET handoff (prefetch distance ~3
// iters > L2-hit latency), af in-place reload (one-full-offset slack),
// T prefetched one offset ahead, XCD-bijective tile swizzle.
// R12 change: y is stored as BF16 (was f32) -> halves y-write and the
// following bn_relu read (84MB/layer traffic cut). Stats still from f32.
// ---------------------------------------------------------------------------
__global__ __launch_bounds__(256) void subm_conv_kernel(
    const unsigned short* __restrict__ xin,   // (M+1) x 128 bf16, row M zeros
    const unsigned short* __restrict__ Wp,    // 27 x 16 x 128 x 8 bf16 packed
    const int* __restrict__ T, const unsigned* __restrict__ act64,
    unsigned short* __restrict__ yout, float* __restrict__ stats, int M)
{
    const int tid = threadIdx.x;
    const int lane = tid & 63;
    const int w = tid >> 6;

    // ---- T1: bijective XCD swizzle (m204): contiguous tile chunk per XCD ----
    const int nwg = gridDim.x;
    const int orig = blockIdx.x;
    const int xcd = orig & 7;
    const int q8 = nwg >> 3, r8 = nwg & 7;
    const int tile = (xcd < r8 ? xcd * (q8 + 1) : r8 * (q8 + 1) + (xcd - r8) * q8) + (orig >> 3);

    const int m0 = tile * 256;
    const int rw = w * 64;           // 64 rows per wave (2 row-blocks of 32)
    const int q = lane >> 5;
    const int l31 = lane & 31;
    int row0 = m0 + rw + l31;
    int row1 = row0 + 32;
    if (row0 >= M) row0 = M - 1;  // gather table guard (stores guarded below)
    if (row1 >= M) row1 = M - 1;

    f32x16 acc0[4], acc1[4];
#pragma unroll
    for (int t = 0; t < 4; ++t)
#pragma unroll
        for (int r = 0; r < 16; ++r) { acc0[t][r] = 0.f; acc1[t][r] = 0.f; }

    const uint4* xin4 = (const uint4*)xin;
    const bf16x8* WpB = (const bf16x8*)Wp;

    unsigned amask = act64[tile * 4 + w];  // per-wave mask

    if (amask) {
        // ---- prologue: first offset's gathers + pipe slots 0..2 ----
        int o = __ffs(amask) - 1; amask &= amask - 1;
        int h0 = T[o * M + row0], h1 = T[o * M + row1];
        uint4 af0[8], af1[8];
#pragma unroll
        for (int j = 0; j < 8; ++j) {
            af0[j] = xin4[h0 * 16 + 2 * j + q];
            af1[j] = xin4[h1 * 16 + 2 * j + q];
        }
        int o1 = -1;
        if (amask) {
            o1 = __ffs(amask) - 1; amask &= amask - 1;
            h0 = T[o1 * M + row0]; h1 = T[o1 * M + row1];
        }

        const bf16x8* Bo = WpB + (size_t)o * 2048;
        bf16x8 bp[4][4];
#pragma unroll
        for (int s = 0; s < 3; ++s) {
            int kb = (s << 1) | q;
            bp[s][0] = Bo[kb * 128 + l31];
            bp[s][1] = Bo[kb * 128 + 32 + l31];
            bp[s][2] = Bo[kb * 128 + 64 + l31];
            bp[s][3] = Bo[kb * 128 + 96 + l31];
        }

        while (true) {
            // ---- prefetch T for the offset after next (hidden under MFMA) ----
            int o2 = -1, i0 = 0, i1 = 0;
            if (amask) {
                o2 = __ffs(amask) - 1; amask &= amask - 1;
                i0 = T[o2 * M + row0]; i1 = T[o2 * M + row1];
            }

            const bool more = (o1 >= 0);
            const bf16x8* Bn = WpB + (size_t)(more ? o1 : o) * 2048;

            __builtin_amdgcn_s_setprio(1);
#pragma unroll
            for (int ks = 0; ks < 8; ++ks) {
                const int cs = ks & 3;        // consume slot (holds position ks)
                const int ls = (ks + 3) & 3;  // load slot (position ks+3)
                bf16x8 bc0 = bp[cs][0], bc1 = bp[cs][1], bc2 = bp[cs][2], bc3 = bp[cs][3];
                if (ks < 5) {
                    int kb = ((ks + 3) << 1) | q;
                    bp[ls][0] = Bo[kb * 128 + l31];
                    bp[ls][1] = Bo[kb * 128 + 32 + l31];
                    bp[ls][2] = Bo[kb * 128 + 64 + l31];
                    bp[ls][3] = Bo[kb * 128 + 96 + l31];
                } else if (more) {
                    // cross-offset handoff: pre-fill next offset's ks 0..2
                    int kb = ((ks - 5) << 1) | q;
                    bp[ls][0] = Bn[kb * 128 + l31];
                    bp[ls][1] = Bn[kb * 128 + 32 + l31];
                    bp[ls][2] = Bn[kb * 128 + 64 + l31];
                    bp[ls][3] = Bn[kb * 128 + 96 + l31];
                }
                bf16x8 a0 = *(const bf16x8*)&af0[ks];
                bf16x8 a1 = *(const bf16x8*)&af1[ks];
                if (more) {
                    // af[ks] just went dead: reload with next offset's rows.
                    af0[ks] = xin4[h0 * 16 + 2 * ks + q];
                    af1[ks] = xin4[h1 * 16 + 2 * ks + q];
                }
                acc0[0] = __builtin_amdgcn_mfma_f32_32x32x16_bf16(a0, bc0, acc0[0], 0, 0, 0);
                acc1[0] = __builtin_amdgcn_mfma_f32_32x32x16_bf16(a1, bc0, acc1[0], 0, 0, 0);
                acc0[1] = __builtin_amdgcn_mfma_f32_32x32x16_bf16(a0, bc1, acc0[1], 0, 0, 0);
                acc1[1] = __builtin_amdgcn_mfma_f32_32x32x16_bf16(a1, bc1, acc1[1], 0, 0, 0);
                acc0[2] = __builtin_amdgcn_mfma_f32_32x32x16_bf16(a0, bc2, acc0[2], 0, 0, 0);
                acc1[2] = __builtin_amdgcn_mfma_f32_32x32x16_bf16(a1, bc2, acc1[2], 0, 0, 0);
                acc0[3] = __builtin_amdgcn_mfma_f32_32x32x16_bf16(a0, bc3, acc0[3], 0, 0, 0);
                acc1[3] = __builtin_amdgcn_mfma_f32_32x32x16_bf16(a1, bc3, acc1[3], 0, 0, 0);
            }
            __builtin_amdgcn_s_setprio(0);

            if (!more) break;
            o = o1; o1 = o2; h0 = i0; h1 = i1;
            Bo = Bn;
        }
    }

    // ---- epilogue: store y (bf16) + BN stats (tail rows contribute 0) ----
#pragma unroll
    for (int tn = 0; tn < 4; ++tn) {
        int col = tn * 32 + l31;
        float s = 0.f, sq = 0.f;
#pragma unroll
        for (int r = 0; r < 16; ++r) {
            int rloc = (r & 3) + 8 * (r >> 2) + 4 * q + rw;
            int grow = m0 + rloc;
            float v = (grow < M) ? acc0[tn][r] : 0.f;
            if (grow < M) yout[grow * 128 + col] = (unsigned short)f2bf_rne(v);
            s += v; sq += v * v;
        }
#pragma unroll
        for (int r = 0; r < 16; ++r) {
            int rloc = (r & 3) + 8 * (r >> 2) + 4 * q + rw + 32;
            int grow = m0 + rloc;
            float v = (grow < M) ? acc1[tn][r] : 0.f;
            if (grow < M) yout[grow * 128 + col] = (unsigned short)f2bf_rne(v);
            s += v; sq += v * v;
        }
        s += __shfl_xor(s, 32);
        sq += __shfl_xor(sq, 32);
        if (lane < 32) {
            atomicAdd(&stats[col], s);
            atomicAdd(&stats[128 + col], sq);
        }
    }
}

// ---------------------------------------------------------------------------
// BN (batch stats) + ReLU -> bf16 (optionally + residual). y input is bf16.
// ---------------------------------------------------------------------------
__global__ void bn_relu_kernel(const unsigned short* __restrict__ y, const float* __restrict__ stats,
                               const float* __restrict__ g, const float* __restrict__ b,
                               unsigned short* __restrict__ out, int total4, float invM) {
    int idx = blockIdx.x * 256 + threadIdx.x;
    if (idx >= total4) return;
    int e0 = idx * 4;
    int c0 = e0 & 127;
    uint2 yv = *(const uint2*)(y + e0);
    float yp[4];
    yp[0] = __uint_as_float(yv.x << 16);
    yp[1] = __uint_as_float(yv.x & 0xffff0000u);
    yp[2] = __uint_as_float(yv.y << 16);
    yp[3] = __uint_as_float(yv.y & 0xffff0000u);
    float h[4];
#pragma unroll
    for (int j = 0; j < 4; ++j) {
        int c = c0 + j;
        float mean = stats[c] * invM;
        float var = stats[128 + c] * invM - mean * mean;
        float sc = g[c] * rsqrtf(var + LN_EPS);
        float sh = b[c] - mean * sc;
        float vv = yp[j] * sc + sh;
        h[j] = vv > 0.f ? vv : 0.f;
    }
    uint2 pk;
    pk.x = f2bf_rne(h[0]) | (f2bf_rne(h[1]) << 16);
    pk.y = f2bf_rne(h[2]) | (f2bf_rne(h[3]) << 16);
    *(uint2*)(out + e0) = pk;
}

__global__ void bn_relu_res_kernel(const unsigned short* __restrict__ y, const float* __restrict__ stats,
                                   const float* __restrict__ g, const float* __restrict__ b,
                                   const unsigned short* __restrict__ idn,
                                   unsigned short* __restrict__ out, int total4, float invM) {
    int idx = blockIdx.x * 256 + threadIdx.x;
    if (idx >= total4) return;
    int e0 = idx * 4;
    int c0 = e0 & 127;
    uint2 yv = *(const uint2*)(y + e0);
    float yp[4];
    yp[0] = __uint_as_float(yv.x << 16);
    yp[1] = __uint_as_float(yv.x & 0xffff0000u);
    yp[2] = __uint_as_float(yv.y << 16);
    yp[3] = __uint_as_float(yv.y & 0xffff0000u);
    uint2 iv = *(const uint2*)(idn + e0);
    float id[4];
    id[0] = __uint_as_float(iv.x << 16);
    id[1] = __uint_as_float(iv.x & 0xffff0000u);
    id[2] = __uint_as_float(iv.y << 16);
    id[3] = __uint_as_float(iv.y & 0xffff0000u);
    float h[4];
#pragma unroll
    for (int j = 0; j < 4; ++j) {
        int c = c0 + j;
        float mean = stats[c] * invM;
        float var = stats[128 + c] * invM - mean * mean;
        float sc = g[c] * rsqrtf(var + LN_EPS);
        float sh = b[c] - mean * sc;
        float vv = yp[j] * sc + sh + id[j];
        h[j] = vv > 0.f ? vv : 0.f;
    }
    uint2 pk;
    pk.x = f2bf_rne(h[0]) | (f2bf_rne(h[1]) << 16);
    pk.y = f2bf_rne(h[2]) | (f2bf_rne(h[3]) << 16);
    *(uint2*)(out + e0) = pk;
}

// ---------------------------------------------------------------------------
// Head over voxels: Dv = relu(A @ w1 + b1) @ w2   (per-voxel, M x 14)
// ---------------------------------------------------------------------------
__global__ __launch_bounds__(256) void head_vox_kernel(
    const unsigned short* __restrict__ A,    // (M+1) x 128 bf16
    const unsigned short* __restrict__ Wp1,  // 8 x 64 x 8 bf16 packed
    const float* __restrict__ b1, const float* __restrict__ w2,
    const float* __restrict__ b2, float* __restrict__ Dv, int M)
{
    __shared__ uint4 W1s[1024];              // 16 KB (uint4: 16B-aligned reads)
    __shared__ unsigned short Hs[8192];      // 128 x 64 bf16, chunk-swizzled, 16 KB
    __shared__ float w2s[896];               // 64 x 14

    const int tid = threadIdx.x;
    const int lane = tid & 63;
    const int w = tid >> 6;
    const int m0 = blockIdx.x * 128;
    const int rw = w * 32;
    const int q = lane >> 5;
    const int l31 = lane & 31;
    int myrow = m0 + rw + l31;
    if (myrow > M) myrow = M;  // row M is zeros

    for (int i = tid; i < 1024; i += 256) W1s[i] = ((const uint4*)Wp1)[i];
    for (int i = tid; i < 896; i += 256) w2s[i] = w2[i];

    const uint4* xin4 = (const uint4*)A;
    uint4 af[8];
#pragma unroll
    for (int j = 0; j < 8; ++j) af[j] = xin4[myrow * 16 + 2 * j + q];

    f32x16 acc[2];
#pragma unroll
    for (int t = 0; t < 2; ++t)
#pragma unroll
        for (int r = 0; r < 16; ++r) acc[t][r] = 0.f;

    __syncthreads();

#pragma unroll
    for (int ks = 0; ks < 8; ++ks) {
        int kb = (ks << 1) | q;
        bf16x8 a = *(const bf16x8*)&af[ks];
#pragma unroll
        for (int tn = 0; tn < 2; ++tn) {
            bf16x8 b = ((const bf16x8*)W1s)[kb * 64 + tn * 32 + l31];
            acc[tn] = __builtin_amdgcn_mfma_f32_32x32x16_bf16(a, b, acc[tn], 0, 0, 0);
        }
    }

#pragma unroll
    for (int tn = 0; tn < 2; ++tn) {
        int col = tn * 32 + l31;
        float bias = b1[col];
        int ch = col >> 3, ce = col & 7;
#pragma unroll
        for (int r = 0; r < 16; ++r) {
            int rloc = (r & 3) + 8 * (r >> 2) + 4 * q + rw;
            float v = acc[tn][r] + bias;
            v = v > 0.f ? v : 0.f;
            Hs[rloc * 64 + (ch ^ (rloc & 7)) * 8 + ce] = (unsigned short)f2bf_rne(v);
        }
    }
    __syncthreads();

    int r2 = tid >> 1;
    int c0 = (tid & 1) * 7;
    float o[7];
#pragma unroll
    for (int j = 0; j < 7; ++j) o[j] = b2[c0 + j];
#pragma unroll
    for (int c = 0; c < 8; ++c) {
        bf16x8 hv = ((const bf16x8*)Hs)[r2 * 8 + (c ^ (r2 & 7))];
#pragma unroll
        for (int e = 0; e < 8; ++e) {
            float h = bf2f(((const unsigned short*)&hv)[e]);
            int k = c * 8 + e;
#pragma unroll
            for (int j = 0; j < 7; ++j) o[j] = fmaf(h, w2s[k * 14 + c0 + j], o[j]);
        }
    }
    int grow = m0 + r2;
    if (grow < M) {
#pragma unroll
        for (int j = 0; j < 7; ++j) Dv[grow * 14 + c0 + j] = o[j];
    }
}

// out[p] = gp[p,:14] + Dv[inv_idx[p]]
__global__ void head_scatter_kernel(const float* __restrict__ gp, const float* __restrict__ Dv,
                                    const int* __restrict__ inv_idx, float* __restrict__ out, int N) {
    int p = blockIdx.x * 256 + threadIdx.x;
    if (p >= N) return;
    int vx = inv_idx[p];
#pragma unroll
    for (int c = 0; c < 14; ++c) out[p * 14 + c] = gp[p * 14 + c] + Dv[vx * 14 + c];
}

// ---------------------------------------------------------------------------
extern "C" void kernel_launch(void* const* d_in, const int* in_sizes, int n_in,
                              void* d_out, int out_size, void* d_ws, size_t ws_size,
                              hipStream_t stream) {
    const float* gp       = (const float*)d_in[0];
    const float* w_enc    = (const float*)d_in[1];
    const float* b_enc    = (const float*)d_in[2];
    const float* ln_g     = (const float*)d_in[3];
    const float* ln_b     = (const float*)d_in[4];
    const float* conv_w   = (const float*)d_in[5];
    const float* bn_g     = (const float*)d_in[6];
    const float* bn_b     = (const float*)d_in[7];
    const float* w1       = (const float*)d_in[8];
    const float* b1       = (const float*)d_in[9];
    const float* w2       = (const float*)d_in[10];
    const float* b2       = (const float*)d_in[11];
    const float* nbr_mask = (const float*)d_in[12];
    const int*   inv_idx  = (const int*)d_in[13];
    const int*   nbr_idx  = (const int*)d_in[14];

    const int N = in_sizes[0] / 14;
    const int M = in_sizes[12] / 27;
    const int ntiles = (M + 127) / 128;      // 128-row tiling (head_vox)
    const int ntiles256 = (M + 255) / 256;   // 256-row tiling (subm_conv)

    char* ws = (char*)d_ws;
    size_t off = 0;
    unsigned short* Wp = (unsigned short*)(ws + off); off += (size_t)4 * 27 * 16384 * 2;
    unsigned short* A  = (unsigned short*)(ws + off); off += (size_t)(M + 1) * 128 * 2;
    unsigned short* H  = (unsigned short*)(ws + off); off += (size_t)(M + 1) * 128 * 2;
    float* Yraw  = (float*)(ws + off);                    // vsum f32 / y bf16 / Dv f32
    unsigned short* Ybf = (unsigned short*)(ws + off);
    size_t zoff = off;
    off += (size_t)M * 128 * 4;
    float* cnt   = (float*)(ws + off); off += (size_t)M * 4;
    float* stats = (float*)(ws + off); off += 4 * 256 * 4;
    unsigned* act64 = (unsigned*)(ws + off); off += (size_t)ntiles256 * 4 * 4;
    size_t zbytes = off - zoff;
    int* T = (int*)(ws + off); off += (size_t)27 * M * 4;
    unsigned short* Wp1 = (unsigned short*)(ws + off); off += 8192 * 2;
    float* Dv = Yraw;

    hipMemsetAsync(Yraw, 0, zbytes, stream);
    hipMemsetAsync(A + (size_t)M * 128, 0, 256, stream);
    hipMemsetAsync(H + (size_t)M * 128, 0, 256, stream);

    const int E = 4 * 27 * 128 * 128;
    pack_w_kernel<<<(E + 255) / 256, 256, 0, stream>>>(conv_w, Wp, E);
    pack_w1_kernel<<<32, 256, 0, stream>>>(w1, Wp1);
    prep_nbr_kernel<<<(M + 255) / 256, 256, 0, stream>>>(nbr_idx, nbr_mask, T, act64, M);
    encode_kernel<<<(N + 3) / 4, 256, 0, stream>>>(gp, w_enc, b_enc, ln_g, ln_b, inv_idx, Yraw, cnt, N);
    const int total4 = M * 32;
    vox_mean_kernel<<<(total4 + 255) / 256, 256, 0, stream>>>(Yraw, cnt, A, total4);

    const float invM = 1.f / (float)M;
    for (int blk = 0; blk < 2; ++blk) {
        int c0 = 2 * blk, c1 = 2 * blk + 1;
        subm_conv_kernel<<<ntiles256, 256, 0, stream>>>(
            A, Wp + (size_t)c0 * 27 * 16384, T, act64, Ybf, stats + c0 * 256, M);
        bn_relu_kernel<<<(total4 + 255) / 256, 256, 0, stream>>>(
            Ybf, stats + c0 * 256, bn_g + c0 * 128, bn_b + c0 * 128, H, total4, invM);
        subm_conv_kernel<<<ntiles256, 256, 0, stream>>>(
            H, Wp + (size_t)c1 * 27 * 16384, T, act64, Ybf, stats + c1 * 256, M);
        bn_relu_res_kernel<<<(total4 + 255) / 256, 256, 0, stream>>>(
            Ybf, stats + c1 * 256, bn_g + c1 * 128, bn_b + c1 * 128, A, A, total4, invM);
    }
    head_vox_kernel<<<ntiles, 256, 0, stream>>>(A, Wp1, b1, w2, b2, Dv, M);
    head_scatter_kernel<<<(N + 255) / 256, 256, 0, stream>>>(gp, Dv, inv_idx, (float*)d_out, N);
}